// Round 1
// baseline (85.195 us; speedup 1.0000x reference)
//
#include <hip/hip_runtime.h>
#include <hip/hip_bf16.h>
#include <math.h>

// Dempster-Shafer evidential forward — fused single kernel (R6, resubmit for profile).
//   input [B,C,H,W,D] f32, W [K,C], BETA [K,M], alpha [K,1], gamma [K,1]
//   out   [B,M+1,H,W,D] f32;  K=20, C=16, M=4, B=2.
//
// Closed form (R4): P_m = prod_k (1 - c_m[k]*e_k), O = prod_k (1 - a_k*e_k),
//   e_k = 2^arg_k, arg_k = dot(x, g^2*log2e*W_k) - 0.5*g^2*log2e*(||x||^2+||W_k||^2).
// Dot via v_mfma_f32_32x32x16_bf16: A=Wp[32x16 protos x ch], B=X[16 ch x 32 elems];
// C/D col=lane&31=elem, row=(r&3)+8*(r>>2)+4*half=proto; halves hold disjoint proto
// subsets, merged by shfl_xor(32). Bias folded via rank-2 second MFMA. (R5, verified.)
//
// R6 changes vs R5:
//  - prep fused into main kernel (LDS constants, one __syncthreads) — one launch.
//  - the TSTEP loop's `if (base>=BS) break` removed (grid covers BS exactly) and
//    ALL tiles' global loads hand-hoisted ahead of compute. R5's break blocked
//    load speculation -> serial {load,wait,compute} rounds = latency-bound.
//  - TSTEP=2 so the prefetch fits 128-VGPR budget; stores split across halves.
#define NK 20
#define NC 16
#define NM 4
#define TSTEP 2

typedef __attribute__((ext_vector_type(8)))  short  short8;
typedef __attribute__((ext_vector_type(16))) float  floatx16;

static __device__ __forceinline__ short bf16b(float f) {
    __hip_bfloat16 h = __float2bfloat16(f);
    return *reinterpret_cast<short*>(&h);
}

__global__ __launch_bounds__(256, 4) void ds_fused(
    const float* __restrict__ inp,
    const float* __restrict__ Wg,
    const float* __restrict__ BETAg,
    const float* __restrict__ alphag,
    const float* __restrict__ gammag,
    float* __restrict__ out,
    int S,        // H*W*D = 262144
    int BS)       // B*S
{
    __shared__ __align__(16) float sCst[32][8];   // {c0,c1,c2,c3,a,0,0,0} per proto
    __shared__ __align__(16) short sWpb[32][16];  // bf16(g2L*W), zero-padded rows 20..31
    __shared__ short sA2[32][2];                  // bf16{nh, nbk}

    const int t = threadIdx.x;
    if (t < 32) {
        if (t < NK) {
            const float L   = 1.4426950408889634f;   // log2(e)
            const float g   = gammag[t];
            const float g2L = g * g * L;
            float w2 = 0.f;
            #pragma unroll
            for (int c = 0; c < NC; ++c) {
                const float w = Wg[t*NC + c];
                sWpb[t][c] = bf16b(g2L * w);
                w2 = fmaf(w, w, w2);
            }
            const float a = 0.99f / (1.0f + __expf(-alphag[t]));
            float b0 = BETAg[t*NM+0], b1 = BETAg[t*NM+1], b2 = BETAg[t*NM+2], b3 = BETAg[t*NM+3];
            b0 *= b0; b1 *= b1; b2 *= b2; b3 *= b3;
            const float uinv = 1.0f / (b0 + b1 + b2 + b3);
            sCst[t][0] = (1.0f - b0*uinv) * a;
            sCst[t][1] = (1.0f - b1*uinv) * a;
            sCst[t][2] = (1.0f - b2*uinv) * a;
            sCst[t][3] = (1.0f - b3*uinv) * a;
            sCst[t][4] = a;
            sCst[t][5] = 0.f; sCst[t][6] = 0.f; sCst[t][7] = 0.f;
            sA2[t][0] = bf16b(-0.5f * g2L);
            sA2[t][1] = bf16b(-0.5f * g2L * w2);
        } else {
            #pragma unroll
            for (int i = 0; i < 8; ++i) sCst[t][i] = 0.f;
            #pragma unroll
            for (int c = 0; c < NC; ++c) sWpb[t][c] = 0;
            sA2[t][0] = 0; sA2[t][1] = 0;
        }
    }
    __syncthreads();

    const int lane = t & 63;
    const int half = lane >> 5;
    const int col  = lane & 31;
    const int gw   = blockIdx.x * 4 + (t >> 6);
    const int ebase = gw * (TSTEP * 32);          // wave's first element

    // ---- prefetch ALL tiles' x values (no conditionals; grid covers BS exactly)
    // S is a multiple of 64 -> batch index is uniform across the wave's 64 elems.
    const int b  = (ebase >= S) ? 1 : 0;
    const int spw = ebase - b * S;
    const float* xb0 = inp + (size_t)b * NC * S + spw + col;
    float xv[TSTEP][8];
    #pragma unroll
    for (int tt = 0; tt < TSTEP; ++tt)
        #pragma unroll
        for (int j = 0; j < 8; ++j)
            xv[tt][j] = xb0[(size_t)(8*half + j) * S + tt*32];

    // ---- wave-invariant fragments / constants
    const short8 afrag = *(const short8*)&sWpb[col][half*8];
    short8 a2frag;
    #pragma unroll
    for (int j = 0; j < 8; ++j) a2frag[j] = 0;
    if (half == 0) { a2frag[0] = sA2[col][0]; a2frag[1] = sA2[col][1]; }

    float cm0[12], cm1[12], cm2[12], cm3[12], cO[12];
    #pragma unroll
    for (int r = 0; r < 12; ++r) {
        const int p = (r & 3) + 8*(r >> 2) + 4*half;
        const float4 cv = *(const float4*)&sCst[p][0];
        cm0[r] = cv.x; cm1[r] = cv.y; cm2[r] = cv.z; cm3[r] = cv.w;
        cO[r]  = sCst[p][4];
    }

    #pragma unroll
    for (int tt = 0; tt < TSTEP; ++tt) {
        const int sp = spw + tt*32 + col;

        short8 bfrag;
        float x2p = 0.f;
        #pragma unroll
        for (int j = 0; j < 8; ++j) {
            const float v = xv[tt][j];
            x2p = fmaf(v, v, x2p);
            bfrag[j] = bf16b(v);
        }
        const float x2 = x2p + __shfl_xor(x2p, 32, 64);

        short8 b2frag;
        #pragma unroll
        for (int j = 0; j < 8; ++j) b2frag[j] = 0;
        if (half == 0) { b2frag[0] = bf16b(x2); b2frag[1] = (short)0x3F80; }  // [x2, 1.0]

        floatx16 acc;
        #pragma unroll
        for (int i = 0; i < 16; ++i) acc[i] = 0.f;
        acc = __builtin_amdgcn_mfma_f32_32x32x16_bf16(afrag,  bfrag,  acc, 0, 0, 0);
        acc = __builtin_amdgcn_mfma_f32_32x32x16_bf16(a2frag, b2frag, acc, 0, 0, 0);

        float P0 = 1.f, P1 = 1.f, P2 = 1.f, P3 = 1.f, PO = 1.f;
        #pragma unroll
        for (int r = 0; r < 12; ++r) {
            const float ek = __builtin_amdgcn_exp2f(acc[r]);
            P0 *= fmaf(-cm0[r], ek, 1.0f);
            P1 *= fmaf(-cm1[r], ek, 1.0f);
            P2 *= fmaf(-cm2[r], ek, 1.0f);
            P3 *= fmaf(-cm3[r], ek, 1.0f);
            PO *= fmaf(-cO[r],  ek, 1.0f);
        }
        // merge the halves' disjoint proto subsets
        P0 *= __shfl_xor(P0, 32, 64);
        P1 *= __shfl_xor(P1, 32, 64);
        P2 *= __shfl_xor(P2, 32, 64);
        P3 *= __shfl_xor(P3, 32, 64);
        PO *= __shfl_xor(PO, 32, 64);

        const float O  = PO;
        const float f0 = P0 - O, f1 = P1 - O, f2 = P2 - O, f3 = P3 - O;
        const float inv = 1.0f / (f0 + f1 + f2 + f3 + O);

        float* op = out + (size_t)b * (NM+1) * S + sp;
        if (half == 0) {
            op[0]           = f0 * inv;
            op[(size_t)S]   = f1 * inv;
            op[(size_t)2*S] = f2 * inv;
        } else {
            op[(size_t)3*S] = f3 * inv;
            op[(size_t)4*S] = O  * inv;
        }
    }
}

extern "C" void kernel_launch(void* const* d_in, const int* in_sizes, int n_in,
                              void* d_out, int out_size, void* d_ws, size_t ws_size,
                              hipStream_t stream) {
    const float* inp   = (const float*)d_in[0];
    const float* Wg    = (const float*)d_in[1];
    const float* BETAg = (const float*)d_in[2];
    const float* alphag= (const float*)d_in[3];
    const float* gammag= (const float*)d_in[4];
    float* out = (float*)d_out;

    const int BS = in_sizes[0] / NC;   // B*S = 524288
    const int S  = BS / 2;             // 262144 (B=2 fixed by setup_inputs)

    // one wave covers TSTEP*32 = 64 elems; 4 waves/block -> 256 elems/block
    const int elems_per_block = 4 * TSTEP * 32;
    const int grid = (BS + elems_per_block - 1) / elems_per_block;  // 2048, exact
    ds_fused<<<grid, 256, 0, stream>>>(inp, Wg, BETAg, alphag, gammag, out, S, BS);
}

// Round 2
// 84.049 us; speedup vs baseline: 1.0136x; 1.0136x over previous
//
#include <hip/hip_runtime.h>
#include <hip/hip_bf16.h>
#include <math.h>

// Dempster-Shafer evidential forward — fused single kernel (R7).
//   input [B,C,H,W,D] f32, W [K,C], BETA [K,M], alpha [K,1], gamma [K,1]
//   out   [B,M+1,H,W,D] f32;  K=20, C=16, M=4, B=2.
//
// Closed form: P_m = prod_k (1 - c_m[k]*e_k), O = prod_k (1 - a_k*e_k),
//   e_k = 2^(g2L*(x.W_k) - 0.5*g2L*||x||^2) with the constant 2^(-0.5*g2L*||W_k||^2)
//   folded multiplicatively into c_m[k] and a_k (R7; exponent split is safe:
//   g2L*(x.w - x^2/2) <= g2L*w^2/2 ~ 0.12 for this data, no overflow).
// Dot via v_mfma_f32_32x32x16_bf16: A=Wp[32x16 protos x ch], B=X[16 ch x 32 elems];
// C/D col=lane&31=elem, row=(r&3)+8*(r>>2)+4*half=proto (verified prev session).
//
// R7 changes vs R6 (theory: R6 was ~40us, 4-5x above the ~9us model; prime
// suspect VGPR spill from 60 resident constant regs at the 128-VGPR cap):
//  - product-loop constants read from LDS per iteration (2 wave-uniform addrs =
//    free broadcast) instead of 5x12 hoisted VGPR arrays -> spill impossible.
//  - ||x||^2 shuffle eliminated: second MFMA computes nh*sum(x_c^2) directly
//    (a2 = nh in all 16 K-slots, b2 = bf16(x_c^2); MFMA K-sum spans both halves).
//  - protos remapped 10+10 across the two half-subsets -> product loop is 10
//    iterations uniformly (was 12 incl. 4 dead protos), no half divergence.
#define NK 20
#define NC 16
#define NM 4
#define TSTEP 2

typedef __attribute__((ext_vector_type(8)))  short  short8;
typedef __attribute__((ext_vector_type(16))) float  floatx16;

static __device__ __forceinline__ short bf16b(float f) {
    __hip_bfloat16 h = __float2bfloat16(f);
    return *reinterpret_cast<short*>(&h);
}

__global__ __launch_bounds__(256, 4) void ds_fused(
    const float* __restrict__ inp,
    const float* __restrict__ Wg,
    const float* __restrict__ BETAg,
    const float* __restrict__ alphag,
    const float* __restrict__ gammag,
    float* __restrict__ out,
    int S,        // H*W*D = 262144
    int BS)       // B*S
{
    __shared__ __align__(16) float sCst[32][8];   // {c0,c1,c2,c3,aO,0,0,0} per C-row
    __shared__ __align__(16) short sWpb[32][16];  // bf16(g2L*W) by C-row, zero elsewhere
    __shared__ short sNh[32];                     // bf16(-0.5*g2L) per C-row

    const int t = threadIdx.x;

    // ---- prep: zero all 32 rows, then scatter the 20 protos to their C-rows.
    if (t < 32) {
        #pragma unroll
        for (int i = 0; i < 8; ++i) sCst[t][i] = 0.f;
        #pragma unroll
        for (int c = 0; c < NC; ++c) sWpb[t][c] = 0;
        sNh[t] = 0;
    }
    __syncthreads();
    if (t < NK) {
        const float L   = 1.4426950408889634f;   // log2(e)
        const float g   = gammag[t];
        const float g2L = g * g * L;
        // proto t -> C-row: t<10 in half0's rows {0-3,8-11,16,17},
        //                   t>=10 in half1's rows {4-7,12-15,20,21}.
        const int tm  = (t < 10) ? t : (t - 10);
        const int row = (tm & 3) + 8 * (tm >> 2) + ((t < 10) ? 0 : 4);
        float w2 = 0.f;
        #pragma unroll
        for (int c = 0; c < NC; ++c) {
            const float w = Wg[t*NC + c];
            sWpb[row][c] = bf16b(g2L * w);
            w2 = fmaf(w, w, w2);
        }
        const float nh = -0.5f * g2L;
        sNh[row] = bf16b(nh);
        const float p2nbk = exp2f(nh * w2);                 // 2^(-0.5*g2L*||W||^2)
        const float a  = 0.99f / (1.0f + __expf(-alphag[t]));
        const float ap = a * p2nbk;                         // bias folded in
        float b0 = BETAg[t*NM+0], b1 = BETAg[t*NM+1], b2 = BETAg[t*NM+2], b3 = BETAg[t*NM+3];
        b0 *= b0; b1 *= b1; b2 *= b2; b3 *= b3;
        const float uinv = 1.0f / (b0 + b1 + b2 + b3);
        sCst[row][0] = (1.0f - b0*uinv) * ap;
        sCst[row][1] = (1.0f - b1*uinv) * ap;
        sCst[row][2] = (1.0f - b2*uinv) * ap;
        sCst[row][3] = (1.0f - b3*uinv) * ap;
        sCst[row][4] = ap;
    }
    __syncthreads();

    const int lane = t & 63;
    const int half = lane >> 5;
    const int col  = lane & 31;
    const int gw   = blockIdx.x * 4 + (t >> 6);
    const int ebase = gw * (TSTEP * 32);          // wave's first element

    // ---- prefetch ALL tiles' x values (grid covers BS exactly; S % 64 == 0
    // so the batch index is uniform across the wave's elements).
    const int b   = (ebase >= S) ? 1 : 0;
    const int spw = ebase - b * S;
    const float* xb0 = inp + (size_t)b * NC * S + spw + col;
    float xv[TSTEP][8];
    #pragma unroll
    for (int tt = 0; tt < TSTEP; ++tt)
        #pragma unroll
        for (int j = 0; j < 8; ++j)
            xv[tt][j] = xb0[(size_t)(8*half + j) * S + tt*32];

    // ---- wave-invariant fragments
    const short8 afrag = *(const short8*)&sWpb[col][half*8];
    const short  nhb   = sNh[col];
    short8 nhfrag;
    #pragma unroll
    for (int j = 0; j < 8; ++j) nhfrag[j] = nhb;

    #pragma unroll
    for (int tt = 0; tt < TSTEP; ++tt) {
        const int sp = spw + tt*32 + col;

        short8 bfrag, b2frag;
        #pragma unroll
        for (int j = 0; j < 8; ++j) {
            const float v = xv[tt][j];
            bfrag[j]  = bf16b(v);
            b2frag[j] = bf16b(v * v);
        }

        floatx16 acc;
        #pragma unroll
        for (int i = 0; i < 16; ++i) acc[i] = 0.f;
        acc = __builtin_amdgcn_mfma_f32_32x32x16_bf16(afrag,  bfrag,  acc, 0, 0, 0);
        acc = __builtin_amdgcn_mfma_f32_32x32x16_bf16(nhfrag, b2frag, acc, 0, 0, 0);

        float P0 = 1.f, P1 = 1.f, P2 = 1.f, P3 = 1.f, PO = 1.f;
        #pragma unroll
        for (int r = 0; r < 10; ++r) {
            const int p = (r & 3) + 8*(r >> 2) + 4*half;     // live C-row for this half
            const float4 cv = *(const float4*)&sCst[p][0];   // LDS broadcast (2 addrs/wave)
            const float  aO = sCst[p][4];
            const float  ek = __builtin_amdgcn_exp2f(acc[r]);
            P0 *= fmaf(-cv.x, ek, 1.0f);
            P1 *= fmaf(-cv.y, ek, 1.0f);
            P2 *= fmaf(-cv.z, ek, 1.0f);
            P3 *= fmaf(-cv.w, ek, 1.0f);
            PO *= fmaf(-aO,   ek, 1.0f);
        }
        // merge the halves' disjoint proto subsets
        P0 *= __shfl_xor(P0, 32, 64);
        P1 *= __shfl_xor(P1, 32, 64);
        P2 *= __shfl_xor(P2, 32, 64);
        P3 *= __shfl_xor(P3, 32, 64);
        PO *= __shfl_xor(PO, 32, 64);

        const float O  = PO;
        const float f0 = P0 - O, f1 = P1 - O, f2 = P2 - O, f3 = P3 - O;
        const float inv = 1.0f / (f0 + f1 + f2 + f3 + O);

        float* op = out + (size_t)b * (NM+1) * S + sp;
        if (half == 0) {
            op[0]           = f0 * inv;
            op[(size_t)S]   = f1 * inv;
            op[(size_t)2*S] = f2 * inv;
        } else {
            op[(size_t)3*S] = f3 * inv;
            op[(size_t)4*S] = O  * inv;
        }
    }
}

extern "C" void kernel_launch(void* const* d_in, const int* in_sizes, int n_in,
                              void* d_out, int out_size, void* d_ws, size_t ws_size,
                              hipStream_t stream) {
    const float* inp   = (const float*)d_in[0];
    const float* Wg    = (const float*)d_in[1];
    const float* BETAg = (const float*)d_in[2];
    const float* alphag= (const float*)d_in[3];
    const float* gammag= (const float*)d_in[4];
    float* out = (float*)d_out;

    const int BS = in_sizes[0] / NC;   // B*S = 524288
    const int S  = BS / 2;             // 262144 (B=2 fixed by setup_inputs)

    // one wave covers TSTEP*32 = 64 elems; 4 waves/block -> 256 elems/block
    const int elems_per_block = 4 * TSTEP * 32;
    const int grid = (BS + elems_per_block - 1) / elems_per_block;  // 2048, exact
    ds_fused<<<grid, 256, 0, stream>>>(inp, Wg, BETAg, alphag, gammag, out, S, BS);
}